// Round 1
// baseline (817.438 us; speedup 1.0000x reference)
//
#include <hip/hip_runtime.h>

#define IN_FEATS 768

// ---------------------------------------------------------------------------
// Kernel 1: fused linear layer 1.
// Computes hn1 = x @ W_neigh1.T  (cols 0..31 of combined GEMM)
//          hs1 = x @ W_self1.T + b1 (cols 32..63)
// Tiled GEMM: 64 rows x 64 cols per block, K-chunks of 16, 4x4 micro-tile.
// ---------------------------------------------------------------------------
__global__ __launch_bounds__(256) void gemm1_kernel(
    const float* __restrict__ x,     // [N,768]
    const float* __restrict__ Wn,    // [32,768]
    const float* __restrict__ Ws,    // [32,768]
    const float* __restrict__ b1,    // [32]
    float* __restrict__ hn1,         // [N,32]
    float* __restrict__ hs1,         // [N,32]
    int N)
{
    __shared__ float As[16][68];   // [k][row], +4 pad keeps rows 16B-aligned (272B)
    __shared__ float Bs[16][68];   // [k][col]

    const int tid  = threadIdx.x;
    const int tx   = tid & 15;     // col group (x4)
    const int ty   = tid >> 4;     // row group (x4)
    const int lrow = tid >> 2;     // 0..63 (load row / weight row)
    const int lk4  = (tid & 3) * 4;
    const int row0 = blockIdx.x * 64;

    float acc[4][4];
#pragma unroll
    for (int i = 0; i < 4; ++i)
#pragma unroll
        for (int j = 0; j < 4; ++j) acc[i][j] = 0.0f;

    const int  grow   = row0 + lrow;
    const bool rvalid = (grow < N);
    const float* xrow = x + (size_t)(rvalid ? grow : (N - 1)) * IN_FEATS;
    const float* wrow = (lrow < 32) ? (Wn + (size_t)lrow * IN_FEATS)
                                    : (Ws + (size_t)(lrow - 32) * IN_FEATS);

    for (int k0 = 0; k0 < IN_FEATS; k0 += 16) {
        float4 av = rvalid ? *(const float4*)(xrow + k0 + lk4)
                           : make_float4(0.f, 0.f, 0.f, 0.f);
        float4 bv = *(const float4*)(wrow + k0 + lk4);
        As[lk4 + 0][lrow] = av.x;
        As[lk4 + 1][lrow] = av.y;
        As[lk4 + 2][lrow] = av.z;
        As[lk4 + 3][lrow] = av.w;
        Bs[lk4 + 0][lrow] = bv.x;
        Bs[lk4 + 1][lrow] = bv.y;
        Bs[lk4 + 2][lrow] = bv.z;
        Bs[lk4 + 3][lrow] = bv.w;
        __syncthreads();
#pragma unroll
        for (int kk = 0; kk < 16; ++kk) {
            float4 a = *(const float4*)&As[kk][ty * 4];
            float4 b = *(const float4*)&Bs[kk][tx * 4];
            acc[0][0] += a.x * b.x; acc[0][1] += a.x * b.y; acc[0][2] += a.x * b.z; acc[0][3] += a.x * b.w;
            acc[1][0] += a.y * b.x; acc[1][1] += a.y * b.y; acc[1][2] += a.y * b.z; acc[1][3] += a.y * b.w;
            acc[2][0] += a.z * b.x; acc[2][1] += a.z * b.y; acc[2][2] += a.z * b.z; acc[2][3] += a.z * b.w;
            acc[3][0] += a.w * b.x; acc[3][1] += a.w * b.y; acc[3][2] += a.w * b.z; acc[3][3] += a.w * b.w;
        }
        __syncthreads();
    }

#pragma unroll
    for (int i = 0; i < 4; ++i) {
        const int r = row0 + ty * 4 + i;
        if (r >= N) continue;
        if (tx < 8) {
            float4 v = make_float4(acc[i][0], acc[i][1], acc[i][2], acc[i][3]);
            *(float4*)(hn1 + (size_t)r * 32 + tx * 4) = v;
        } else {
            const int c = tx * 4 - 32;
            float4 v = make_float4(acc[i][0] + b1[c + 0], acc[i][1] + b1[c + 1],
                                   acc[i][2] + b1[c + 2], acc[i][3] + b1[c + 3]);
            *(float4*)(hs1 + (size_t)r * 32 + c) = v;
        }
    }
}

// ---------------------------------------------------------------------------
// Kernel 2: edge aggregation, layer 1. 32 lanes per edge.
// agg1[dst] += hn1[src]  (32 floats), deg[dst] += 1
// ---------------------------------------------------------------------------
__global__ __launch_bounds__(256) void edge1_kernel(
    const int* __restrict__ src, const int* __restrict__ dst,
    const float* __restrict__ hn1,
    float* __restrict__ agg1, float* __restrict__ deg, int E)
{
    const long long t = (long long)blockIdx.x * blockDim.x + threadIdx.x;
    const long long e = t >> 5;
    const int l = (int)(t & 31);
    if (e >= E) return;
    const int s = src[e];
    const int d = dst[e];
    const float v = hn1[(size_t)s * 32 + l];
    atomicAdd(&agg1[(size_t)d * 32 + l], v);
    if (l == 0) atomicAdd(&deg[d], 1.0f);
}

// ---------------------------------------------------------------------------
// Kernel 3: finish layer 1 (mean + self + relu) and apply layer-2 linears.
// h = relu(hs1 + agg1/max(deg,1))
// hn2 = h @ W_neigh2.T ; hs2 = h @ W_self2.T + b2
// ---------------------------------------------------------------------------
__global__ __launch_bounds__(256) void layer2_lin_kernel(
    const float* __restrict__ hs1, const float* __restrict__ agg1,
    const float* __restrict__ deg,
    const float* __restrict__ Wn2,   // [8,32]
    const float* __restrict__ Ws2,   // [8,32]
    const float* __restrict__ b2,    // [8]
    float* __restrict__ hn2,         // [N,8]
    float* __restrict__ hs2,         // [N,8]
    int N)
{
    __shared__ float wn[8][32];
    __shared__ float wsm[8][32];
    __shared__ float bb[8];
    const int tid = threadIdx.x;
    wn[tid >> 5][tid & 31]  = Wn2[tid];
    wsm[tid >> 5][tid & 31] = Ws2[tid];
    if (tid < 8) bb[tid] = b2[tid];
    __syncthreads();

    const int n = blockIdx.x * blockDim.x + tid;
    if (n >= N) return;

    const float inv = 1.0f / fmaxf(deg[n], 1.0f);
    float h[32];
#pragma unroll
    for (int q = 0; q < 8; ++q) {
        float4 a = *(const float4*)(agg1 + (size_t)n * 32 + q * 4);
        float4 s = *(const float4*)(hs1 + (size_t)n * 32 + q * 4);
        h[q * 4 + 0] = fmaxf(s.x + a.x * inv, 0.0f);
        h[q * 4 + 1] = fmaxf(s.y + a.y * inv, 0.0f);
        h[q * 4 + 2] = fmaxf(s.z + a.z * inv, 0.0f);
        h[q * 4 + 3] = fmaxf(s.w + a.w * inv, 0.0f);
    }

    float on[8], os[8];
#pragma unroll
    for (int j = 0; j < 8; ++j) {
        float sn = 0.0f, ss = 0.0f;
#pragma unroll
        for (int k = 0; k < 32; ++k) {
            sn += wn[j][k] * h[k];
            ss += wsm[j][k] * h[k];
        }
        on[j] = sn;
        os[j] = ss + bb[j];
    }
    *(float4*)(hn2 + (size_t)n * 8 + 0) = make_float4(on[0], on[1], on[2], on[3]);
    *(float4*)(hn2 + (size_t)n * 8 + 4) = make_float4(on[4], on[5], on[6], on[7]);
    *(float4*)(hs2 + (size_t)n * 8 + 0) = make_float4(os[0], os[1], os[2], os[3]);
    *(float4*)(hs2 + (size_t)n * 8 + 4) = make_float4(os[4], os[5], os[6], os[7]);
}

// ---------------------------------------------------------------------------
// Kernel 4: edge aggregation, layer 2. 8 lanes per edge.
// agg2[dst] += hn2[src]  (8 floats)
// ---------------------------------------------------------------------------
__global__ __launch_bounds__(256) void edge2_kernel(
    const int* __restrict__ src, const int* __restrict__ dst,
    const float* __restrict__ hn2,
    float* __restrict__ agg2, int E)
{
    const long long t = (long long)blockIdx.x * blockDim.x + threadIdx.x;
    const long long e = t >> 3;
    const int l = (int)(t & 7);
    if (e >= E) return;
    const int s = src[e];
    const int d = dst[e];
    const float v = hn2[(size_t)s * 8 + l];
    atomicAdd(&agg2[(size_t)d * 8 + l], v);
}

// ---------------------------------------------------------------------------
// Kernel 5: final combine: out = hs2 + agg2/max(deg,1)
// ---------------------------------------------------------------------------
__global__ __launch_bounds__(256) void finish_kernel(
    const float* __restrict__ hs2, const float* __restrict__ agg2,
    const float* __restrict__ deg, float* __restrict__ out, int N)
{
    const int n = blockIdx.x * blockDim.x + threadIdx.x;
    if (n >= N) return;
    const float inv = 1.0f / fmaxf(deg[n], 1.0f);
    float4 a0 = *(const float4*)(agg2 + (size_t)n * 8 + 0);
    float4 a1 = *(const float4*)(agg2 + (size_t)n * 8 + 4);
    float4 s0 = *(const float4*)(hs2 + (size_t)n * 8 + 0);
    float4 s1 = *(const float4*)(hs2 + (size_t)n * 8 + 4);
    float4 o0 = make_float4(s0.x + a0.x * inv, s0.y + a0.y * inv,
                            s0.z + a0.z * inv, s0.w + a0.w * inv);
    float4 o1 = make_float4(s1.x + a1.x * inv, s1.y + a1.y * inv,
                            s1.z + a1.z * inv, s1.w + a1.w * inv);
    *(float4*)(out + (size_t)n * 8 + 0) = o0;
    *(float4*)(out + (size_t)n * 8 + 4) = o1;
}

extern "C" void kernel_launch(void* const* d_in, const int* in_sizes, int n_in,
                              void* d_out, int out_size, void* d_ws, size_t ws_size,
                              hipStream_t stream)
{
    const float* feats = (const float*)d_in[0];
    const int*   src   = (const int*)d_in[1];
    const int*   dst   = (const int*)d_in[2];
    const float* Ws1   = (const float*)d_in[3];  // W_self1 [32,768]
    const float* Wn1   = (const float*)d_in[4];  // W_neigh1 [32,768]
    const float* b1    = (const float*)d_in[5];
    const float* Ws2   = (const float*)d_in[6];  // W_self2 [8,32]
    const float* Wn2   = (const float*)d_in[7];  // W_neigh2 [8,32]
    const float* b2    = (const float*)d_in[8];
    float* out = (float*)d_out;

    const int N = in_sizes[0] / IN_FEATS;   // 100000
    const int E = in_sizes[1];              // 3200000

    // Workspace layout (floats)
    float* wsf  = (float*)d_ws;
    const size_t N32 = (size_t)N * 32;
    const size_t N8  = (size_t)N * 8;
    float* hn1  = wsf;               // [N,32]
    float* hs1  = hn1 + N32;         // [N,32]
    float* agg1 = hs1 + N32;         // [N,32]
    float* deg  = agg1 + N32;        // [N]
    float* hn2  = deg + N;           // [N,8]
    float* hs2  = hn2 + N8;          // [N,8]
    float* agg2 = hs2 + N8;          // [N,8]

    // Zero the accumulators (agg1 + deg are contiguous; agg2 separate).
    hipMemsetAsync(agg1, 0, (N32 + (size_t)N) * sizeof(float), stream);
    hipMemsetAsync(agg2, 0, N8 * sizeof(float), stream);

    // 1) layer-1 fused GEMM
    {
        dim3 grid((N + 63) / 64);
        gemm1_kernel<<<grid, 256, 0, stream>>>(feats, Wn1, Ws1, b1, hn1, hs1, N);
    }
    // 2) layer-1 edge aggregation (+degree)
    {
        long long threads = (long long)E * 32;
        dim3 grid((unsigned)((threads + 255) / 256));
        edge1_kernel<<<grid, 256, 0, stream>>>(src, dst, hn1, agg1, deg, E);
    }
    // 3) finish layer 1 + layer-2 linears
    {
        dim3 grid((N + 255) / 256);
        layer2_lin_kernel<<<grid, 256, 0, stream>>>(hs1, agg1, deg, Wn2, Ws2, b2,
                                                    hn2, hs2, N);
    }
    // 4) layer-2 edge aggregation
    {
        long long threads = (long long)E * 8;
        dim3 grid((unsigned)((threads + 255) / 256));
        edge2_kernel<<<grid, 256, 0, stream>>>(src, dst, hn2, agg2, E);
    }
    // 5) final combine
    {
        dim3 grid((N + 255) / 256);
        finish_kernel<<<grid, 256, 0, stream>>>(hs2, agg2, deg, out, N);
    }
}

// Round 2
// 585.177 us; speedup vs baseline: 1.3969x; 1.3969x over previous
//
#include <hip/hip_runtime.h>

#define IN_FEATS 768

// ---------------------------------------------------------------------------
// Kernel 1: fused linear layer 1 (unchanged from round 1).
// hn1 = x @ W_neigh1.T ; hs1 = x @ W_self1.T + b1
// ---------------------------------------------------------------------------
__global__ __launch_bounds__(256) void gemm1_kernel(
    const float* __restrict__ x,
    const float* __restrict__ Wn,
    const float* __restrict__ Ws,
    const float* __restrict__ b1,
    float* __restrict__ hn1,
    float* __restrict__ hs1,
    int N)
{
    __shared__ float As[16][68];
    __shared__ float Bs[16][68];

    const int tid  = threadIdx.x;
    const int tx   = tid & 15;
    const int ty   = tid >> 4;
    const int lrow = tid >> 2;
    const int lk4  = (tid & 3) * 4;
    const int row0 = blockIdx.x * 64;

    float acc[4][4];
#pragma unroll
    for (int i = 0; i < 4; ++i)
#pragma unroll
        for (int j = 0; j < 4; ++j) acc[i][j] = 0.0f;

    const int  grow   = row0 + lrow;
    const bool rvalid = (grow < N);
    const float* xrow = x + (size_t)(rvalid ? grow : (N - 1)) * IN_FEATS;
    const float* wrow = (lrow < 32) ? (Wn + (size_t)lrow * IN_FEATS)
                                    : (Ws + (size_t)(lrow - 32) * IN_FEATS);

    for (int k0 = 0; k0 < IN_FEATS; k0 += 16) {
        float4 av = rvalid ? *(const float4*)(xrow + k0 + lk4)
                           : make_float4(0.f, 0.f, 0.f, 0.f);
        float4 bv = *(const float4*)(wrow + k0 + lk4);
        As[lk4 + 0][lrow] = av.x;
        As[lk4 + 1][lrow] = av.y;
        As[lk4 + 2][lrow] = av.z;
        As[lk4 + 3][lrow] = av.w;
        Bs[lk4 + 0][lrow] = bv.x;
        Bs[lk4 + 1][lrow] = bv.y;
        Bs[lk4 + 2][lrow] = bv.z;
        Bs[lk4 + 3][lrow] = bv.w;
        __syncthreads();
#pragma unroll
        for (int kk = 0; kk < 16; ++kk) {
            float4 a = *(const float4*)&As[kk][ty * 4];
            float4 b = *(const float4*)&Bs[kk][tx * 4];
            acc[0][0] += a.x * b.x; acc[0][1] += a.x * b.y; acc[0][2] += a.x * b.z; acc[0][3] += a.x * b.w;
            acc[1][0] += a.y * b.x; acc[1][1] += a.y * b.y; acc[1][2] += a.y * b.z; acc[1][3] += a.y * b.w;
            acc[2][0] += a.z * b.x; acc[2][1] += a.z * b.y; acc[2][2] += a.z * b.z; acc[2][3] += a.z * b.w;
            acc[3][0] += a.w * b.x; acc[3][1] += a.w * b.y; acc[3][2] += a.w * b.z; acc[3][3] += a.w * b.w;
        }
        __syncthreads();
    }

#pragma unroll
    for (int i = 0; i < 4; ++i) {
        const int r = row0 + ty * 4 + i;
        if (r >= N) continue;
        if (tx < 8) {
            float4 v = make_float4(acc[i][0], acc[i][1], acc[i][2], acc[i][3]);
            *(float4*)(hn1 + (size_t)r * 32 + tx * 4) = v;
        } else {
            const int c = tx * 4 - 32;
            float4 v = make_float4(acc[i][0] + b1[c + 0], acc[i][1] + b1[c + 1],
                                   acc[i][2] + b1[c + 2], acc[i][3] + b1[c + 3]);
            *(float4*)(hs1 + (size_t)r * 32 + c) = v;
        }
    }
}

// ---------------------------------------------------------------------------
// CSR construction: histogram -> exclusive scan -> scatter
// ---------------------------------------------------------------------------
__global__ __launch_bounds__(256) void hist_kernel(
    const int* __restrict__ dst, int* __restrict__ cnt, int E)
{
    const int e = blockIdx.x * blockDim.x + threadIdx.x;
    if (e < E) atomicAdd(&cnt[dst[e]], 1);
}

__global__ __launch_bounds__(256) void scan_part_kernel(
    const int* __restrict__ cnt, int* __restrict__ partial, int N)
{
    __shared__ int sdata[256];
    const int t = threadIdx.x;
    const int base = blockIdx.x * 1024 + t * 4;
    int s = 0;
#pragma unroll
    for (int k = 0; k < 4; ++k) {
        const int i = base + k;
        if (i < N) s += cnt[i];
    }
    sdata[t] = s;
    __syncthreads();
    for (int off = 128; off > 0; off >>= 1) {
        if (t < off) sdata[t] += sdata[t + off];
        __syncthreads();
    }
    if (t == 0) partial[blockIdx.x] = sdata[0];
}

__global__ void scan_mid_kernel(int* __restrict__ partial, int nb)
{
    if (threadIdx.x == 0 && blockIdx.x == 0) {
        int run = 0;
        for (int b = 0; b < nb; ++b) {
            const int v = partial[b];
            partial[b] = run;
            run += v;
        }
    }
}

__global__ __launch_bounds__(256) void scan_write_kernel(
    const int* __restrict__ cnt, const int* __restrict__ partial,
    int* __restrict__ rowstart, int N, int E)
{
    __shared__ int sdata[256];
    const int t = threadIdx.x;
    const int base = blockIdx.x * 1024 + t * 4;
    int v[4];
    int s = 0;
#pragma unroll
    for (int k = 0; k < 4; ++k) {
        const int i = base + k;
        v[k] = (i < N) ? cnt[i] : 0;
        s += v[k];
    }
    sdata[t] = s;
    __syncthreads();
    // inclusive Hillis-Steele scan over 256 entries
    for (int off = 1; off < 256; off <<= 1) {
        const int add = (t >= off) ? sdata[t - off] : 0;
        __syncthreads();
        sdata[t] += add;
        __syncthreads();
    }
    int excl = (t > 0 ? sdata[t - 1] : 0) + partial[blockIdx.x];
#pragma unroll
    for (int k = 0; k < 4; ++k) {
        const int i = base + k;
        if (i < N) { rowstart[i] = excl; excl += v[k]; }
    }
    if (blockIdx.x == 0 && t == 0) rowstart[N] = E;
}

__global__ __launch_bounds__(256) void scatter_kernel(
    const int* __restrict__ src, const int* __restrict__ dst,
    const int* __restrict__ rowstart, int* __restrict__ cursor,
    int* __restrict__ edge_src, int E)
{
    const int e = blockIdx.x * blockDim.x + threadIdx.x;
    if (e >= E) return;
    const int d = dst[e];
    const int p = atomicAdd(&cursor[d], 1);
    edge_src[rowstart[d] + p] = src[e];
}

// ---------------------------------------------------------------------------
// Kernel: CSR aggregation layer 1, fused with mean+self+relu and layer-2
// linears. 8 nodes per block, 32 lanes per node (one lane per feature).
// ---------------------------------------------------------------------------
__global__ __launch_bounds__(256) void agg1_fused_kernel(
    const float* __restrict__ hn1, const float* __restrict__ hs1,
    const int* __restrict__ rowstart, const int* __restrict__ edge_src,
    const float* __restrict__ Wn2,   // [8,32]
    const float* __restrict__ Ws2,   // [8,32]
    const float* __restrict__ b2,    // [8]
    float* __restrict__ hn2,         // [N,8]
    float* __restrict__ hs2,         // [N,8]
    int N)
{
    __shared__ float w2[16][32];     // rows 0..7: Wn2, rows 8..15: Ws2
    __shared__ float bb[8];
    __shared__ float hsm[8][33];     // per-node hidden vector (pad to kill conflicts)

    const int tid  = threadIdx.x;
    const int g    = tid >> 5;       // node slot in block, 0..7
    const int lane = tid & 31;       // feature index

    w2[g][lane]     = Wn2[tid];
    w2[8 + g][lane] = Ws2[tid];
    if (tid < 8) bb[tid] = b2[tid];

    const int n = blockIdx.x * 8 + g;
    float h = 0.0f;
    if (n < N) {
        const int rs = rowstart[n];
        const int re = rowstart[n + 1];
        float sum = 0.0f;
        int e = rs;
        for (; e + 4 <= re; e += 4) {
            const int s0 = edge_src[e + 0];
            const int s1 = edge_src[e + 1];
            const int s2 = edge_src[e + 2];
            const int s3 = edge_src[e + 3];
            const float v0 = hn1[(size_t)s0 * 32 + lane];
            const float v1 = hn1[(size_t)s1 * 32 + lane];
            const float v2 = hn1[(size_t)s2 * 32 + lane];
            const float v3 = hn1[(size_t)s3 * 32 + lane];
            sum += (v0 + v1) + (v2 + v3);
        }
        for (; e < re; ++e)
            sum += hn1[(size_t)edge_src[e] * 32 + lane];
        const float inv = 1.0f / fmaxf((float)(re - rs), 1.0f);
        h = fmaxf(hs1[(size_t)n * 32 + lane] + sum * inv, 0.0f);
    }
    hsm[g][lane] = h;
    __syncthreads();

    // 16 active lanes per node: lane j<8 -> hn2 col j, j in 8..15 -> hs2 col j-8
    if (n < N && lane < 16) {
        const float* w = w2[lane];
        const float* hv = hsm[g];
        float acc = 0.0f;
#pragma unroll
        for (int k = 0; k < 32; ++k) acc += w[k] * hv[k];
        if (lane < 8) hn2[(size_t)n * 8 + lane] = acc;
        else          hs2[(size_t)n * 8 + (lane - 8)] = acc + bb[lane - 8];
    }
}

// ---------------------------------------------------------------------------
// Kernel: CSR aggregation layer 2, fused with final combine -> d_out.
// 8 nodes per block; per node: 4 edge-slots x 8 features.
// ---------------------------------------------------------------------------
__global__ __launch_bounds__(256) void agg2_fused_kernel(
    const float* __restrict__ hn2, const float* __restrict__ hs2,
    const int* __restrict__ rowstart, const int* __restrict__ edge_src,
    float* __restrict__ out, int N)
{
    const int tid  = threadIdx.x;
    const int g    = tid >> 5;
    const int lane = tid & 31;
    const int slot = lane >> 3;      // 0..3
    const int f    = lane & 7;       // 0..7

    const int n = blockIdx.x * 8 + g;
    float sum = 0.0f;
    int deg = 0;
    if (n < N) {
        const int rs = rowstart[n];
        const int re = rowstart[n + 1];
        deg = re - rs;
        for (int e = rs + slot; e < re; e += 4) {
            const int s = edge_src[e];
            sum += hn2[(size_t)s * 8 + f];
        }
    }
    // reduce the 4 slots (lanes f, f+8, f+16, f+24 within the 32-lane group)
    sum += __shfl_xor(sum, 8, 64);
    sum += __shfl_xor(sum, 16, 64);

    if (n < N && slot == 0) {
        const float inv = 1.0f / fmaxf((float)deg, 1.0f);
        out[(size_t)n * 8 + f] = hs2[(size_t)n * 8 + f] + sum * inv;
    }
}

extern "C" void kernel_launch(void* const* d_in, const int* in_sizes, int n_in,
                              void* d_out, int out_size, void* d_ws, size_t ws_size,
                              hipStream_t stream)
{
    const float* feats = (const float*)d_in[0];
    const int*   src   = (const int*)d_in[1];
    const int*   dst   = (const int*)d_in[2];
    const float* Ws1   = (const float*)d_in[3];
    const float* Wn1   = (const float*)d_in[4];
    const float* b1    = (const float*)d_in[5];
    const float* Ws2   = (const float*)d_in[6];
    const float* Wn2   = (const float*)d_in[7];
    const float* b2    = (const float*)d_in[8];
    float* out = (float*)d_out;

    const int N = in_sizes[0] / IN_FEATS;   // 100000
    const int E = in_sizes[1];              // 3200000

    // Workspace layout
    float* wsf = (float*)d_ws;
    const size_t N32 = (size_t)N * 32;
    const size_t N8  = (size_t)N * 8;
    float* hn1 = wsf;                 // [N,32]
    float* hs1 = hn1 + N32;           // [N,32]
    float* hn2 = hs1 + N32;           // [N,8]
    float* hs2 = hn2 + N8;            // [N,8]
    int* rowstart = (int*)(hs2 + N8); // [N+1]
    int* cnt      = rowstart + (N + 1); // [N]
    int* partial  = cnt + N;            // [128]
    int* edge_src = partial + 128;      // [E]

    const int nbScan = (N + 1023) / 1024;

    // --- CSR build ---
    hipMemsetAsync(cnt, 0, (size_t)N * sizeof(int), stream);
    hist_kernel<<<(E + 255) / 256, 256, 0, stream>>>(dst, cnt, E);
    scan_part_kernel<<<nbScan, 256, 0, stream>>>(cnt, partial, N);
    scan_mid_kernel<<<1, 64, 0, stream>>>(partial, nbScan);
    scan_write_kernel<<<nbScan, 256, 0, stream>>>(cnt, partial, rowstart, N, E);
    hipMemsetAsync(cnt, 0, (size_t)N * sizeof(int), stream);
    scatter_kernel<<<(E + 255) / 256, 256, 0, stream>>>(src, dst, rowstart, cnt,
                                                        edge_src, E);

    // --- layer-1 fused GEMM ---
    gemm1_kernel<<<(N + 63) / 64, 256, 0, stream>>>(feats, Wn1, Ws1, b1,
                                                    hn1, hs1, N);

    // --- layer-1 aggregation + finish + layer-2 linear ---
    agg1_fused_kernel<<<(N + 7) / 8, 256, 0, stream>>>(
        hn1, hs1, rowstart, edge_src, Wn2, Ws2, b2, hn2, hs2, N);

    // --- layer-2 aggregation + final combine ---
    agg2_fused_kernel<<<(N + 7) / 8, 256, 0, stream>>>(
        hn2, hs2, rowstart, edge_src, out, N);
}

// Round 3
// 466.037 us; speedup vs baseline: 1.7540x; 1.2556x over previous
//
#include <hip/hip_runtime.h>
#include <hip/hip_bf16.h>

#define IN_FEATS 768

typedef __attribute__((ext_vector_type(8))) short short8v;
typedef __attribute__((ext_vector_type(4))) float f32x4;

__device__ __forceinline__ unsigned short f2bf(float f) {
    union { float f; unsigned int u; } c; c.f = f;
    unsigned int r = (c.u + 0x7FFFu + ((c.u >> 16) & 1u)) >> 16;  // RNE
    return (unsigned short)r;
}
__device__ __forceinline__ float bflo(unsigned int v) {
    union { unsigned int u; float f; } c; c.u = v << 16; return c.f;
}
__device__ __forceinline__ float bfhi(unsigned int v) {
    union { unsigned int u; float f; } c; c.u = v & 0xFFFF0000u; return c.f;
}

// ---------------------------------------------------------------------------
// Kernel 1: fused layer-1 linear via bf16 MFMA.
// hn1b = bf16(x @ Wn1.T)  [N,32] ; hs1 = x @ Ws1.T + b1 (fp32) [N,32]
// BM=64, BN=64 (cols 0-31: Wn, 32-63: Ws), BK=32, 4 waves, 16x16x32 MFMA.
// ---------------------------------------------------------------------------
__global__ __launch_bounds__(256) void gemm1_kernel(
    const float* __restrict__ x,
    const float* __restrict__ Wn,
    const float* __restrict__ Ws,
    const float* __restrict__ b1,
    unsigned short* __restrict__ hn1b,   // [N,32] bf16 bits
    float* __restrict__ hs1,             // [N,32]
    int N)
{
    __shared__ unsigned short As[64][32];   // [row][k] bf16
    __shared__ unsigned short Bs[64][32];   // [outcol][k] bf16

    const int tid  = threadIdx.x;
    const int lrow = tid >> 2;          // 0..63
    const int lk8  = (tid & 3) * 8;     // 0,8,16,24
    const int row0 = blockIdx.x * 64;

    const int  grow   = row0 + lrow;
    const bool rvalid = (grow < N);
    const float* xrow = x + (size_t)(rvalid ? grow : (N - 1)) * IN_FEATS;
    const float* wrow = (lrow < 32) ? (Wn + (size_t)lrow * IN_FEATS)
                                    : (Ws + (size_t)(lrow - 32) * IN_FEATS);

    const int w    = tid >> 6;          // wave 0..3
    const int l    = tid & 63;
    const int lr16 = l & 15;
    const int lk   = (l >> 4) * 8;

    f32x4 acc[4];
#pragma unroll
    for (int ct = 0; ct < 4; ++ct) acc[ct] = (f32x4){0.f, 0.f, 0.f, 0.f};

    // prologue loads (k0 = 0)
    float4 a0 = *(const float4*)(xrow + lk8);
    float4 a1 = *(const float4*)(xrow + lk8 + 4);
    float4 w0 = *(const float4*)(wrow + lk8);
    float4 w1 = *(const float4*)(wrow + lk8 + 4);

    for (int step = 0; step < IN_FEATS / 32; ++step) {
        // convert + stage current K-slab
        unsigned short* ap = &As[lrow][lk8];
        ap[0] = f2bf(a0.x); ap[1] = f2bf(a0.y); ap[2] = f2bf(a0.z); ap[3] = f2bf(a0.w);
        ap[4] = f2bf(a1.x); ap[5] = f2bf(a1.y); ap[6] = f2bf(a1.z); ap[7] = f2bf(a1.w);
        unsigned short* bp = &Bs[lrow][lk8];
        bp[0] = f2bf(w0.x); bp[1] = f2bf(w0.y); bp[2] = f2bf(w0.z); bp[3] = f2bf(w0.w);
        bp[4] = f2bf(w1.x); bp[5] = f2bf(w1.y); bp[6] = f2bf(w1.z); bp[7] = f2bf(w1.w);
        __syncthreads();

        // issue next slab's global loads (overlap with MFMA section)
        if (step + 1 < IN_FEATS / 32) {
            const int k0 = (step + 1) * 32;
            a0 = *(const float4*)(xrow + k0 + lk8);
            a1 = *(const float4*)(xrow + k0 + lk8 + 4);
            w0 = *(const float4*)(wrow + k0 + lk8);
            w1 = *(const float4*)(wrow + k0 + lk8 + 4);
        }

        short8v afrag = *(const short8v*)&As[w * 16 + lr16][lk];
#pragma unroll
        for (int ct = 0; ct < 4; ++ct) {
            short8v bfrag = *(const short8v*)&Bs[ct * 16 + lr16][lk];
            acc[ct] = __builtin_amdgcn_mfma_f32_16x16x32_bf16(afrag, bfrag, acc[ct], 0, 0, 0);
        }
        __syncthreads();
    }

    // epilogue: D layout col=lane&15, row=(lane>>4)*4+reg
    const int rbase = row0 + w * 16 + (l >> 4) * 4;
#pragma unroll
    for (int ct = 0; ct < 4; ++ct) {
        const int ncol = ct * 16 + lr16;
        if (ncol < 32) {
#pragma unroll
            for (int j = 0; j < 4; ++j) {
                const int r = rbase + j;
                if (r < N) hn1b[(size_t)r * 32 + ncol] = f2bf(acc[ct][j]);
            }
        } else {
            const int c = ncol - 32;
            const float bias = b1[c];
#pragma unroll
            for (int j = 0; j < 4; ++j) {
                const int r = rbase + j;
                if (r < N) hs1[(size_t)r * 32 + c] = acc[ct][j] + bias;
            }
        }
    }
}

// ---------------------------------------------------------------------------
// CSR construction: histogram -> exclusive scan -> scatter
// ---------------------------------------------------------------------------
__global__ __launch_bounds__(256) void hist_kernel(
    const int* __restrict__ dst, int* __restrict__ cnt, int E)
{
    const int e = blockIdx.x * blockDim.x + threadIdx.x;
    if (e < E) atomicAdd(&cnt[dst[e]], 1);
}

__global__ __launch_bounds__(256) void scan_part_kernel(
    const int* __restrict__ cnt, int* __restrict__ partial, int N)
{
    __shared__ int sdata[256];
    const int t = threadIdx.x;
    const int base = blockIdx.x * 1024 + t * 4;
    int s = 0;
#pragma unroll
    for (int k = 0; k < 4; ++k) {
        const int i = base + k;
        if (i < N) s += cnt[i];
    }
    sdata[t] = s;
    __syncthreads();
    for (int off = 128; off > 0; off >>= 1) {
        if (t < off) sdata[t] += sdata[t + off];
        __syncthreads();
    }
    if (t == 0) partial[blockIdx.x] = sdata[0];
}

__global__ void scan_mid_kernel(int* __restrict__ partial, int nb)
{
    if (threadIdx.x == 0 && blockIdx.x == 0) {
        int run = 0;
        for (int b = 0; b < nb; ++b) {
            const int v = partial[b];
            partial[b] = run;
            run += v;
        }
    }
}

__global__ __launch_bounds__(256) void scan_write_kernel(
    const int* __restrict__ cnt, const int* __restrict__ partial,
    int* __restrict__ rowstart, int N, int E)
{
    __shared__ int sdata[256];
    const int t = threadIdx.x;
    const int base = blockIdx.x * 1024 + t * 4;
    int v[4];
    int s = 0;
#pragma unroll
    for (int k = 0; k < 4; ++k) {
        const int i = base + k;
        v[k] = (i < N) ? cnt[i] : 0;
        s += v[k];
    }
    sdata[t] = s;
    __syncthreads();
    for (int off = 1; off < 256; off <<= 1) {
        const int add = (t >= off) ? sdata[t - off] : 0;
        __syncthreads();
        sdata[t] += add;
        __syncthreads();
    }
    int excl = (t > 0 ? sdata[t - 1] : 0) + partial[blockIdx.x];
#pragma unroll
    for (int k = 0; k < 4; ++k) {
        const int i = base + k;
        if (i < N) { rowstart[i] = excl; excl += v[k]; }
    }
    if (blockIdx.x == 0 && t == 0) rowstart[N] = E;
}

__global__ __launch_bounds__(256) void scatter_kernel(
    const int* __restrict__ src, const int* __restrict__ dst,
    const int* __restrict__ rowstart, int* __restrict__ cursor,
    int* __restrict__ edge_src, int E)
{
    const int e = blockIdx.x * blockDim.x + threadIdx.x;
    if (e >= E) return;
    const int d = dst[e];
    const int p = atomicAdd(&cursor[d], 1);
    edge_src[rowstart[d] + p] = src[e];
}

// ---------------------------------------------------------------------------
// agg1 fused: 16 nodes/block, 16 lanes/node, bf16x2 gathers from hn1b.
// h = relu(hs1 + mean(gather)) ; hn2b = bf16(h @ Wn2.T) ; hs2 = h @ Ws2.T + b2
// ---------------------------------------------------------------------------
__global__ __launch_bounds__(256) void agg1_fused_kernel(
    const unsigned short* __restrict__ hn1b, const float* __restrict__ hs1,
    const int* __restrict__ rowstart, const int* __restrict__ edge_src,
    const float* __restrict__ Wn2,   // [8,32]
    const float* __restrict__ Ws2,   // [8,32]
    const float* __restrict__ b2,    // [8]
    unsigned short* __restrict__ hn2b,  // [N,8] bf16 bits
    float* __restrict__ hs2,            // [N,8]
    int N)
{
    __shared__ float w2[16][33];     // rows 0..7 Wn2, 8..15 Ws2 (+1 pad)
    __shared__ float bb[8];
    __shared__ float hsm[16][33];

    const int tid = threadIdx.x;
    const int g   = tid >> 4;        // node slot 0..15
    const int ln  = tid & 15;        // feature-pair lane

    w2[tid >> 5][tid & 31]       = Wn2[tid];
    w2[8 + (tid >> 5)][tid & 31] = Ws2[tid];
    if (tid < 8) bb[tid] = b2[tid];

    const unsigned int* hn1u = (const unsigned int*)hn1b;  // [N][16] packed pairs

    const int n = blockIdx.x * 16 + g;
    float sx = 0.f, sy = 0.f;
    int degi = 0;
    if (n < N) {
        const int rs = rowstart[n];
        const int re = rowstart[n + 1];
        degi = re - rs;
        int e = rs;
        for (; e + 4 <= re; e += 4) {
            const int s0 = edge_src[e + 0];
            const int s1 = edge_src[e + 1];
            const int s2 = edge_src[e + 2];
            const int s3 = edge_src[e + 3];
            const unsigned int v0 = hn1u[(size_t)s0 * 16 + ln];
            const unsigned int v1 = hn1u[(size_t)s1 * 16 + ln];
            const unsigned int v2 = hn1u[(size_t)s2 * 16 + ln];
            const unsigned int v3 = hn1u[(size_t)s3 * 16 + ln];
            sx += (bflo(v0) + bflo(v1)) + (bflo(v2) + bflo(v3));
            sy += (bfhi(v0) + bfhi(v1)) + (bfhi(v2) + bfhi(v3));
        }
        for (; e < re; ++e) {
            const unsigned int v = hn1u[(size_t)edge_src[e] * 16 + ln];
            sx += bflo(v); sy += bfhi(v);
        }
        const float inv = 1.0f / fmaxf((float)degi, 1.0f);
        const float2 hs = *(const float2*)(hs1 + (size_t)n * 32 + 2 * ln);
        hsm[g][2 * ln + 0] = fmaxf(hs.x + sx * inv, 0.0f);
        hsm[g][2 * ln + 1] = fmaxf(hs.y + sy * inv, 0.0f);
    }
    __syncthreads();

    // layer-2 linears: 16 lanes per node -> 16 outputs (8 hn2 + 8 hs2)
    if (n < N) {
        const float* wrow = w2[ln];
        const float* hv   = hsm[g];
        float acc = 0.0f;
#pragma unroll
        for (int k = 0; k < 32; ++k) acc += wrow[k] * hv[k];
        if (ln < 8) hn2b[(size_t)n * 8 + ln] = f2bf(acc);
        else        hs2[(size_t)n * 8 + (ln - 8)] = acc + bb[ln - 8];
    }
}

// ---------------------------------------------------------------------------
// agg2 fused: 16 nodes/block; per node 4 edge-slots x 4 feat-pair lanes.
// out = hs2 + mean(gather hn2b)
// ---------------------------------------------------------------------------
__global__ __launch_bounds__(256) void agg2_fused_kernel(
    const unsigned short* __restrict__ hn2b, const float* __restrict__ hs2,
    const int* __restrict__ rowstart, const int* __restrict__ edge_src,
    float* __restrict__ out, int N)
{
    const int tid  = threadIdx.x;
    const int g    = tid >> 4;       // node slot 0..15
    const int ln   = tid & 15;
    const int slot = ln >> 2;        // 0..3
    const int q    = ln & 3;         // feature pair 0..3

    const unsigned int* hn2u = (const unsigned int*)hn2b;  // [N][4]

    const int n = blockIdx.x * 16 + g;
    float sx = 0.f, sy = 0.f;
    int degi = 0;
    if (n < N) {
        const int rs = rowstart[n];
        const int re = rowstart[n + 1];
        degi = re - rs;
        for (int e = rs + slot; e < re; e += 4) {
            const unsigned int v = hn2u[(size_t)edge_src[e] * 4 + q];
            sx += bflo(v); sy += bfhi(v);
        }
    }
    // reduce the 4 slots: lanes q, q+4, q+8, q+12 within the 16-lane group
    sx += __shfl_xor(sx, 4, 64);  sy += __shfl_xor(sy, 4, 64);
    sx += __shfl_xor(sx, 8, 64);  sy += __shfl_xor(sy, 8, 64);

    if (n < N && slot == 0) {
        const float inv = 1.0f / fmaxf((float)degi, 1.0f);
        const float2 s = *(const float2*)(hs2 + (size_t)n * 8 + 2 * q);
        float2 o;
        o.x = s.x + sx * inv;
        o.y = s.y + sy * inv;
        *(float2*)(out + (size_t)n * 8 + 2 * q) = o;
    }
}

extern "C" void kernel_launch(void* const* d_in, const int* in_sizes, int n_in,
                              void* d_out, int out_size, void* d_ws, size_t ws_size,
                              hipStream_t stream)
{
    const float* feats = (const float*)d_in[0];
    const int*   src   = (const int*)d_in[1];
    const int*   dst   = (const int*)d_in[2];
    const float* Ws1   = (const float*)d_in[3];
    const float* Wn1   = (const float*)d_in[4];
    const float* b1    = (const float*)d_in[5];
    const float* Ws2   = (const float*)d_in[6];
    const float* Wn2   = (const float*)d_in[7];
    const float* b2    = (const float*)d_in[8];
    float* out = (float*)d_out;

    const int N = in_sizes[0] / IN_FEATS;   // 100000
    const int E = in_sizes[1];              // 3200000

    // Workspace layout
    char* ws = (char*)d_ws;
    const size_t N32 = (size_t)N * 32;
    const size_t N8  = (size_t)N * 8;
    unsigned short* hn1b = (unsigned short*)ws;            // [N,32] bf16
    ws += ((N32 * 2 + 255) / 256) * 256;
    float* hs1 = (float*)ws;                               // [N,32] f32
    ws += ((N32 * 4 + 255) / 256) * 256;
    unsigned short* hn2b = (unsigned short*)ws;            // [N,8] bf16
    ws += ((N8 * 2 + 255) / 256) * 256;
    float* hs2 = (float*)ws;                               // [N,8] f32
    ws += ((N8 * 4 + 255) / 256) * 256;
    int* rowstart = (int*)ws;                              // [N+1]
    ws += (((size_t)(N + 1) * 4 + 255) / 256) * 256;
    int* cnt = (int*)ws;                                   // [N]
    ws += (((size_t)N * 4 + 255) / 256) * 256;
    int* partial = (int*)ws;                               // [128]
    ws += 128 * 4;
    int* edge_src = (int*)ws;                              // [E]

    const int nbScan = (N + 1023) / 1024;

    // --- CSR build ---
    hipMemsetAsync(cnt, 0, (size_t)N * sizeof(int), stream);
    hist_kernel<<<(E + 255) / 256, 256, 0, stream>>>(dst, cnt, E);
    scan_part_kernel<<<nbScan, 256, 0, stream>>>(cnt, partial, N);
    scan_mid_kernel<<<1, 64, 0, stream>>>(partial, nbScan);
    scan_write_kernel<<<nbScan, 256, 0, stream>>>(cnt, partial, rowstart, N, E);
    hipMemsetAsync(cnt, 0, (size_t)N * sizeof(int), stream);
    scatter_kernel<<<(E + 255) / 256, 256, 0, stream>>>(src, dst, rowstart, cnt,
                                                        edge_src, E);

    // --- layer-1 fused GEMM (bf16 MFMA) ---
    gemm1_kernel<<<(N + 63) / 64, 256, 0, stream>>>(feats, Wn1, Ws1, b1,
                                                    hn1b, hs1, N);

    // --- layer-1 aggregation + finish + layer-2 linear ---
    agg1_fused_kernel<<<(N + 15) / 16, 256, 0, stream>>>(
        hn1b, hs1, rowstart, edge_src, Wn2, Ws2, b2, hn2b, hs2, N);

    // --- layer-2 aggregation + final combine ---
    agg2_fused_kernel<<<(N + 15) / 16, 256, 0, stream>>>(
        hn2b, hs2, rowstart, edge_src, out, N);
}